// Round 1
// baseline (380.146 us; speedup 1.0000x reference)
//
#include <hip/hip_runtime.h>

#define NN  512    // data grid / coefficient count per axis
#define NE  1024   // eval points per axis
#define NBC 64     // batch * channels

// ---------------- device helpers ----------------

__device__ __forceinline__ int findspan(double u, const float* t) {
  if (u >= (double)t[NN]) return NN - 1;            // t[512] == 1.0
  int lo = 3, hi = NN - 1;
  while (lo < hi) {
    int mid = (lo + hi + 1) >> 1;
    if ((double)t[mid] <= u) lo = mid; else hi = mid - 1;
  }
  return lo;
}

// de Boor triangle: 4 nonzero cubic basis values at u, span s (cols s-3..s)
__device__ __forceinline__ void deboor4(double u, const float* t, int s, double* N) {
  double left[4], right[4];
  N[0] = 1.0;
  #pragma unroll
  for (int d = 1; d <= 3; ++d) {
    left[d]  = u - (double)t[s + 1 - d];
    right[d] = (double)t[s + d] - u;
    double saved = 0.0;
    #pragma unroll
    for (int r = 0; r < d; ++r) {
      double temp = N[r] / (right[r + 1] + left[d - r]);
      N[r] = saved + right[r + 1] * temp;
      saved = left[d - r] * temp;
    }
    N[d] = saved;
  }
}

// ---------------- K0: knots, basis tables, banded LU ----------------
// bandG[r][0..2] = L multipliers (cols r-3..r-1), [3] = 1/U[r][r], [4..6] = U[r][r+1..r+3]

__global__ __launch_bounds__(1024) void k_pre(float* __restrict__ bandG,
                                              int* __restrict__ espan,
                                              float4* __restrict__ ebas) {
  __shared__ float t[NN + 8];      // 516 used
  __shared__ float band[NN][8];
  const int tid = threadIdx.x;
  if (tid < NN + 4) {
    double v;
    if (tid < 4) v = -1.0;
    else if (tid >= NN) v = 1.0;
    else v = -1.0 + (2.0 * (tid - 2)) / 511.0;   // uniform interior knots (= sliding mean)
    t[tid] = (float)v;
  }
  __syncthreads();
  { // eval-point basis (all 1024 threads)
    double u = (tid == 0) ? -1.0 : ((tid == NE - 1) ? 1.0 : (-1.0 + (2.0 * tid) / 1023.0));
    int s = findspan(u, t);
    double N[4];
    deboor4(u, t, s, N);
    espan[tid] = s;
    ebas[tid] = make_float4((float)N[0], (float)N[1], (float)N[2], (float)N[3]);
  }
  if (tid < NN) { // data-point basis -> banded collocation row
    double u = (tid == 0) ? -1.0 : ((tid == NN - 1) ? 1.0 : (-1.0 + (2.0 * tid) / 511.0));
    int s = findspan(u, t);
    double N[4];
    deboor4(u, t, s, N);
    #pragma unroll
    for (int d = 0; d < 8; ++d) band[tid][d] = 0.f;
    #pragma unroll
    for (int dd = 0; dd < 4; ++dd) band[tid][s - tid + dd] = (float)N[dd]; // d = col - r + 3
  }
  __syncthreads();
  if (tid == 0) {
    // sequential banded LU (lb=3, ub=3), 7-row register window, LDS prefetch 4+ rows ahead
    float w[7][7];
    #pragma unroll
    for (int a = 0; a < 7; ++a)
      #pragma unroll
      for (int b = 0; b < 7; ++b) w[a][b] = band[a][b];
    for (int r = 0; r < NN; ++r) {
      float rd = 1.0f / w[0][3];
      float l1 = w[1][2] * rd, l2 = w[2][1] * rd, l3 = w[3][0] * rd;
      w[1][2] = l1; w[1][3] -= l1 * w[0][4]; w[1][4] -= l1 * w[0][5]; w[1][5] -= l1 * w[0][6];
      w[2][1] = l2; w[2][2] -= l2 * w[0][4]; w[2][3] -= l2 * w[0][5]; w[2][4] -= l2 * w[0][6];
      w[3][0] = l3; w[3][1] -= l3 * w[0][4]; w[3][2] -= l3 * w[0][5]; w[3][3] -= l3 * w[0][6];
      band[r][0] = w[0][0]; band[r][1] = w[0][1]; band[r][2] = w[0][2];
      band[r][3] = rd;      band[r][4] = w[0][4]; band[r][5] = w[0][5]; band[r][6] = w[0][6];
      #pragma unroll
      for (int a = 0; a < 6; ++a)
        #pragma unroll
        for (int b = 0; b < 7; ++b) w[a][b] = w[a + 1][b];
      int nr = r + 7;
      #pragma unroll
      for (int b = 0; b < 7; ++b) w[6][b] = (nr < NN) ? band[nr][b] : 0.f;
    }
  }
  __syncthreads();
  for (int i = tid; i < NN * 8; i += 1024) bandG[i] = (&band[0][0])[i];
}

// ---------------- forward substitution: L y = b (one column per lane) ----------------

__global__ __launch_bounds__(256) void k_fwd(const float* __restrict__ src,
                                             float* __restrict__ dst,
                                             const float* __restrict__ bandG) {
  const int j = blockIdx.x * 256 + threadIdx.x;
  const size_t base = (size_t)blockIdx.y * (NN * NN);
  const float* __restrict__ S = src + base;
  float* __restrict__ D = dst + base;
  __shared__ float Lb[NN][3];
  for (int i = threadIdx.x; i < NN; i += 256) {
    Lb[i][0] = bandG[i * 8 + 0];
    Lb[i][1] = bandG[i * 8 + 1];
    Lb[i][2] = bandG[i * 8 + 2];
  }
  __syncthreads();
  float c1 = 0.f, c2 = 0.f, c3 = 0.f;   // y_{r-1}, y_{r-2}, y_{r-3}
  float bufA[32], bufB[32];
  #pragma unroll
  for (int q = 0; q < 32; ++q) bufA[q] = S[(size_t)q * NN + j];
  #pragma unroll
  for (int q = 0; q < 32; ++q) bufB[q] = S[(size_t)(32 + q) * NN + j];
  #pragma unroll 1
  for (int b = 0; b < 16; b += 2) {
    {
      const int r0 = b * 32;
      #pragma unroll
      for (int q = 0; q < 32; ++q) {
        const int r = r0 + q;
        float y = bufA[q] - Lb[r][0] * c3 - Lb[r][1] * c2 - Lb[r][2] * c1;
        D[(size_t)r * NN + j] = y;
        c3 = c2; c2 = c1; c1 = y;
      }
      if (b + 2 < 16) {
        const int r0n = (b + 2) * 32;
        #pragma unroll
        for (int q = 0; q < 32; ++q) bufA[q] = S[(size_t)(r0n + q) * NN + j];
      }
    }
    {
      const int r0 = (b + 1) * 32;
      #pragma unroll
      for (int q = 0; q < 32; ++q) {
        const int r = r0 + q;
        float y = bufB[q] - Lb[r][0] * c3 - Lb[r][1] * c2 - Lb[r][2] * c1;
        D[(size_t)r * NN + j] = y;
        c3 = c2; c2 = c1; c1 = y;
      }
      if (b + 3 < 16) {
        const int r0n = (b + 3) * 32;
        #pragma unroll
        for (int q = 0; q < 32; ++q) bufB[q] = S[(size_t)(r0n + q) * NN + j];
      }
    }
  }
}

// ---------------- backward substitution: U x = y ----------------

__global__ __launch_bounds__(256) void k_bwd(const float* __restrict__ src,
                                             float* __restrict__ dst,
                                             const float* __restrict__ bandG) {
  const int j = blockIdx.x * 256 + threadIdx.x;
  const size_t base = (size_t)blockIdx.y * (NN * NN);
  const float* __restrict__ S = src + base;
  float* __restrict__ D = dst + base;
  __shared__ float Ub[NN][4];
  for (int i = threadIdx.x; i < NN; i += 256) {
    Ub[i][0] = bandG[i * 8 + 3];
    Ub[i][1] = bandG[i * 8 + 4];
    Ub[i][2] = bandG[i * 8 + 5];
    Ub[i][3] = bandG[i * 8 + 6];
  }
  __syncthreads();
  float c1 = 0.f, c2 = 0.f, c3 = 0.f;   // x_{r+1}, x_{r+2}, x_{r+3}
  float bufA[32], bufB[32];
  #pragma unroll
  for (int q = 0; q < 32; ++q) bufA[q] = S[(size_t)(511 - q) * NN + j];
  #pragma unroll
  for (int q = 0; q < 32; ++q) bufB[q] = S[(size_t)(479 - q) * NN + j];
  #pragma unroll 1
  for (int b = 0; b < 16; b += 2) {
    {
      const int hi = 511 - 32 * b;
      #pragma unroll
      for (int q = 0; q < 32; ++q) {
        const int r = hi - q;
        float x = (bufA[q] - Ub[r][1] * c1 - Ub[r][2] * c2 - Ub[r][3] * c3) * Ub[r][0];
        D[(size_t)r * NN + j] = x;
        c3 = c2; c2 = c1; c1 = x;
      }
      if (b + 2 < 16) {
        const int hin = 511 - 32 * (b + 2);
        #pragma unroll
        for (int q = 0; q < 32; ++q) bufA[q] = S[(size_t)(hin - q) * NN + j];
      }
    }
    {
      const int hi = 511 - 32 * (b + 1);
      #pragma unroll
      for (int q = 0; q < 32; ++q) {
        const int r = hi - q;
        float x = (bufB[q] - Ub[r][1] * c1 - Ub[r][2] * c2 - Ub[r][3] * c3) * Ub[r][0];
        D[(size_t)r * NN + j] = x;
        c3 = c2; c2 = c1; c1 = x;
      }
      if (b + 3 < 16) {
        const int hin = 511 - 32 * (b + 3);
        #pragma unroll
        for (int q = 0; q < 32; ++q) bufB[q] = S[(size_t)(hin - q) * NN + j];
      }
    }
  }
}

// ------------- backward substitution + fused 64x64 LDS transpose -------------

__global__ __launch_bounds__(64) void k_bwdT(const float* __restrict__ src,
                                             float* __restrict__ dst,
                                             const float* __restrict__ bandG) {
  const int lane = threadIdx.x;
  const int j0 = blockIdx.x * 64;
  const int j = j0 + lane;
  const size_t base = (size_t)blockIdx.y * (NN * NN);
  const float* __restrict__ S = src + base;
  float* __restrict__ D = dst + base;
  __shared__ float Ub[NN][4];
  __shared__ float tile[64][65];   // +1 pad: conflict-free transposed read
  for (int i = lane; i < NN; i += 64) {
    Ub[i][0] = bandG[i * 8 + 3];
    Ub[i][1] = bandG[i * 8 + 4];
    Ub[i][2] = bandG[i * 8 + 5];
    Ub[i][3] = bandG[i * 8 + 6];
  }
  __syncthreads();
  float c1 = 0.f, c2 = 0.f, c3 = 0.f;
  #pragma unroll 1
  for (int half = 0; half < 8; ++half) {
    const int hi = 511 - half * 64;
    float buf[64];
    #pragma unroll
    for (int q = 0; q < 64; ++q) buf[q] = S[(size_t)(hi - q) * NN + j];
    #pragma unroll
    for (int q = 0; q < 64; ++q) {
      const int r = hi - q;
      float x = (buf[q] - Ub[r][1] * c1 - Ub[r][2] * c2 - Ub[r][3] * c3) * Ub[r][0];
      tile[63 - q][lane] = x;
      c3 = c2; c2 = c1; c1 = x;
    }
    __syncthreads();
    const int lo = hi - 63;
    #pragma unroll 4
    for (int tt = 0; tt < 64; ++tt) {
      D[(size_t)(j0 + tt) * NN + lo + lane] = tile[lane][tt];
    }
    __syncthreads();
  }
}

// ------------- fused evaluation: H[p] = sum_q CoefT[q,p]*By[y,q]; out = Bx-sparse * H -------------

__global__ __launch_bounds__(256) void k_eval(const float* __restrict__ CoefT,
                                              float* __restrict__ out,
                                              const int* __restrict__ espan,
                                              const float4* __restrict__ ebas) {
  const int y = blockIdx.x;
  const int bc = blockIdx.y;
  const float* __restrict__ C = CoefT + (size_t)bc * (NN * NN);
  __shared__ float H[NN];
  const int tid = threadIdx.x;
  const int sy = espan[y];
  const float4 wy = ebas[y];
  #pragma unroll
  for (int pp = 0; pp < 2; ++pp) {
    const int p = tid + pp * 256;
    float h = wy.x * C[(size_t)(sy - 3) * NN + p]
            + wy.y * C[(size_t)(sy - 2) * NN + p]
            + wy.z * C[(size_t)(sy - 1) * NN + p]
            + wy.w * C[(size_t)(sy)     * NN + p];
    H[p] = h;
  }
  __syncthreads();
  float* __restrict__ O = out + ((size_t)bc * NE + y) * NE;
  #pragma unroll
  for (int xx = 0; xx < 4; ++xx) {
    const int x = tid + xx * 256;
    const int sx = espan[x];
    const float4 wx = ebas[x];
    O[x] = wx.x * H[sx - 3] + wx.y * H[sx - 2] + wx.z * H[sx - 1] + wx.w * H[sx];
  }
}

// ---------------- host launcher ----------------

extern "C" void kernel_launch(void* const* d_in, const int* in_sizes, int n_in,
                              void* d_out, int out_size, void* d_ws, size_t ws_size,
                              hipStream_t stream) {
  (void)in_sizes; (void)n_in; (void)out_size; (void)ws_size;
  const float* Z = (const float*)d_in[0];
  float* out = (float*)d_out;
  float* wsf = (float*)d_ws;
  float* bandG  = wsf;                              // 4096 floats (16 KB)
  int*   espan  = (int*)(wsf + 4096);               // 1024 ints
  float4* ebas  = (float4*)(wsf + 4096 + 1024);     // 1024 float4 (16B-aligned)
  float* BUF2 = (float*)((char*)d_ws + (1 << 20));  // 64 MB: W1 then CoefT
  float* BUF1 = out;                                // 64 MB scratch inside d_out (dead before k_eval)

  k_pre <<<dim3(1),       dim3(1024), 0, stream>>>(bandG, espan, ebas);
  k_fwd <<<dim3(2, NBC),  dim3(256),  0, stream>>>(Z,    BUF1, bandG);   // L y = Z            (along x-axis)
  k_bwdT<<<dim3(8, NBC),  dim3(64),   0, stream>>>(BUF1, BUF2, bandG);   // U x = y, write X1^T
  k_fwd <<<dim3(2, NBC),  dim3(256),  0, stream>>>(BUF2, BUF1, bandG);   // L y = X1^T         (along y-axis)
  k_bwd <<<dim3(2, NBC),  dim3(256),  0, stream>>>(BUF1, BUF2, bandG);   // U x = y  -> CoefT
  k_eval<<<dim3(NE, NBC), dim3(256),  0, stream>>>(BUF2, out, espan, ebas);
}

// Round 2
// 232.251 us; speedup vs baseline: 1.6368x; 1.6368x over previous
//
#include <hip/hip_runtime.h>

#define NN  512    // data grid / coefficient count per axis
#define NE  1024   // eval points per axis
#define NBC 64     // batch * channels

// ================= compile-time table generation =================
// Mirrors the reference: x = float32 linspace(-1,1,512); knots via float32
// cumsum sliding mean (fitpack_knots); basis via de Boor in double; exact
// banded LU (bw 3/3) in double. All evaluated at COMPILE TIME (constexpr),
// stored in a 36 KB __constant__ blob. Replaces the 175 us serial k_pre.

struct Tables {
  float bandG[NN * 8];   // [r][0..2]=L mults (rows r-3..r-1), [3]=1/U[r][r], [4..6]=U[r][r+1..r+3]
  int   espan[NE];
  float ebas[NE * 4];    // float4-compatible (offset 20480 B, 16-aligned)
};

constexpr int cfindspan(double u, const float* t) {
  if (u >= (double)t[NN]) return NN - 1;          // t[512] == 1.0
  int lo = 3, hi = NN - 1;
  while (lo < hi) {
    int mid = (lo + hi + 1) >> 1;
    if ((double)t[mid] <= u) lo = mid; else hi = mid - 1;
  }
  return lo;
}

constexpr void cdeboor4(double u, const float* t, int s, double* N) {
  double left[4] = {}, right[4] = {};
  N[0] = 1.0; N[1] = 0.0; N[2] = 0.0; N[3] = 0.0;
  for (int d = 1; d <= 3; ++d) {
    left[d]  = u - (double)t[s + 1 - d];
    right[d] = (double)t[s + d] - u;
    double saved = 0.0;
    for (int r = 0; r < d; ++r) {
      double temp = N[r] / (right[r + 1] + left[d - r]);
      N[r] = saved + right[r + 1] * temp;
      saved = left[d - r] * temp;
    }
    N[d] = saved;
  }
}

constexpr Tables make_tables() {
  Tables T{};
  // x grid (float32, matches jnp.linspace(-1,1,512))
  float x[NN] = {};
  for (int i = 0; i < NN; ++i) x[i] = (float)(-1.0 + (2.0 * i) / 511.0);
  x[0] = -1.0f; x[NN - 1] = 1.0f;
  // fitpack knots: float32 cumsum, interior = (cs[4+i]-cs[1+i])/3 (sliding mean of 3)
  float t[NN + 4] = {};   // 516 knots
  {
    float cs[NN + 1] = {};
    for (int i = 0; i < NN; ++i) cs[i + 1] = cs[i] + x[i];
    for (int i = 0; i < NN - 4; ++i) t[4 + i] = (cs[4 + i] - cs[1 + i]) / 3.0f;
    for (int i = 0; i < 4; ++i) { t[i] = -1.0f; t[NN + i] = 1.0f; }
  }
  // banded collocation matrix (double), d = col - r + 3
  double W[NN][7] = {};
  for (int r = 0; r < NN; ++r) {
    double u = (double)x[r];
    int s = cfindspan(u, t);
    double N[4] = {};
    cdeboor4(u, t, s, N);
    for (int dd = 0; dd < 4; ++dd) W[r][s - r + dd] += N[dd];
  }
  // exact banded LU, bandwidth 3/3 (no pivoting; matrix is totally positive)
  for (int r = 0; r < NN; ++r) {
    double rd = 1.0 / W[r][3];
    for (int k = 1; k <= 3; ++k) {
      if (r + k < NN) {
        double l = W[r + k][3 - k] * rd;
        W[r + k][3 - k] = l;
        for (int c = 1; c <= 3; ++c) W[r + k][3 - k + c] -= l * W[r][3 + c];
      }
    }
    T.bandG[r * 8 + 0] = (float)W[r][0];
    T.bandG[r * 8 + 1] = (float)W[r][1];
    T.bandG[r * 8 + 2] = (float)W[r][2];
    T.bandG[r * 8 + 3] = (float)rd;
    T.bandG[r * 8 + 4] = (float)W[r][4];
    T.bandG[r * 8 + 5] = (float)W[r][5];
    T.bandG[r * 8 + 6] = (float)W[r][6];
    T.bandG[r * 8 + 7] = 0.0f;
  }
  // eval-point basis (1024 points, float32 linspace, clip is a no-op)
  for (int i = 0; i < NE; ++i) {
    float xe = (float)(-1.0 + (2.0 * i) / 1023.0);
    if (i == 0) xe = -1.0f;
    if (i == NE - 1) xe = 1.0f;
    double u = (double)xe;
    int s = cfindspan(u, t);
    double N[4] = {};
    cdeboor4(u, t, s, N);
    T.espan[i] = s;
    T.ebas[i * 4 + 0] = (float)N[0];
    T.ebas[i * 4 + 1] = (float)N[1];
    T.ebas[i * 4 + 2] = (float)N[2];
    T.ebas[i * 4 + 3] = (float)N[3];
  }
  return T;
}

__constant__ Tables g_tab = make_tables();

// ---------------- forward substitution: L y = b (one column per lane) ----------------

__global__ __launch_bounds__(256) void k_fwd(const float* __restrict__ src,
                                             float* __restrict__ dst) {
  const int j = blockIdx.x * 256 + threadIdx.x;
  const size_t base = (size_t)blockIdx.y * (NN * NN);
  const float* __restrict__ S = src + base;
  float* __restrict__ D = dst + base;
  __shared__ float Lb[NN][3];
  for (int i = threadIdx.x; i < NN; i += 256) {
    Lb[i][0] = g_tab.bandG[i * 8 + 0];
    Lb[i][1] = g_tab.bandG[i * 8 + 1];
    Lb[i][2] = g_tab.bandG[i * 8 + 2];
  }
  __syncthreads();
  float c1 = 0.f, c2 = 0.f, c3 = 0.f;   // y_{r-1}, y_{r-2}, y_{r-3}
  float bufA[32], bufB[32];
  #pragma unroll
  for (int q = 0; q < 32; ++q) bufA[q] = S[(size_t)q * NN + j];
  #pragma unroll
  for (int q = 0; q < 32; ++q) bufB[q] = S[(size_t)(32 + q) * NN + j];
  #pragma unroll 1
  for (int b = 0; b < 16; b += 2) {
    {
      const int r0 = b * 32;
      #pragma unroll
      for (int q = 0; q < 32; ++q) {
        const int r = r0 + q;
        float y = bufA[q] - Lb[r][0] * c3 - Lb[r][1] * c2 - Lb[r][2] * c1;
        D[(size_t)r * NN + j] = y;
        c3 = c2; c2 = c1; c1 = y;
      }
      if (b + 2 < 16) {
        const int r0n = (b + 2) * 32;
        #pragma unroll
        for (int q = 0; q < 32; ++q) bufA[q] = S[(size_t)(r0n + q) * NN + j];
      }
    }
    {
      const int r0 = (b + 1) * 32;
      #pragma unroll
      for (int q = 0; q < 32; ++q) {
        const int r = r0 + q;
        float y = bufB[q] - Lb[r][0] * c3 - Lb[r][1] * c2 - Lb[r][2] * c1;
        D[(size_t)r * NN + j] = y;
        c3 = c2; c2 = c1; c1 = y;
      }
      if (b + 3 < 16) {
        const int r0n = (b + 3) * 32;
        #pragma unroll
        for (int q = 0; q < 32; ++q) bufB[q] = S[(size_t)(r0n + q) * NN + j];
      }
    }
  }
}

// ---------------- backward substitution: U x = y ----------------

__global__ __launch_bounds__(256) void k_bwd(const float* __restrict__ src,
                                             float* __restrict__ dst) {
  const int j = blockIdx.x * 256 + threadIdx.x;
  const size_t base = (size_t)blockIdx.y * (NN * NN);
  const float* __restrict__ S = src + base;
  float* __restrict__ D = dst + base;
  __shared__ float Ub[NN][4];
  for (int i = threadIdx.x; i < NN; i += 256) {
    Ub[i][0] = g_tab.bandG[i * 8 + 3];
    Ub[i][1] = g_tab.bandG[i * 8 + 4];
    Ub[i][2] = g_tab.bandG[i * 8 + 5];
    Ub[i][3] = g_tab.bandG[i * 8 + 6];
  }
  __syncthreads();
  float c1 = 0.f, c2 = 0.f, c3 = 0.f;   // x_{r+1}, x_{r+2}, x_{r+3}
  float bufA[32], bufB[32];
  #pragma unroll
  for (int q = 0; q < 32; ++q) bufA[q] = S[(size_t)(511 - q) * NN + j];
  #pragma unroll
  for (int q = 0; q < 32; ++q) bufB[q] = S[(size_t)(479 - q) * NN + j];
  #pragma unroll 1
  for (int b = 0; b < 16; b += 2) {
    {
      const int hi = 511 - 32 * b;
      #pragma unroll
      for (int q = 0; q < 32; ++q) {
        const int r = hi - q;
        float x = (bufA[q] - Ub[r][1] * c1 - Ub[r][2] * c2 - Ub[r][3] * c3) * Ub[r][0];
        D[(size_t)r * NN + j] = x;
        c3 = c2; c2 = c1; c1 = x;
      }
      if (b + 2 < 16) {
        const int hin = 511 - 32 * (b + 2);
        #pragma unroll
        for (int q = 0; q < 32; ++q) bufA[q] = S[(size_t)(hin - q) * NN + j];
      }
    }
    {
      const int hi = 511 - 32 * (b + 1);
      #pragma unroll
      for (int q = 0; q < 32; ++q) {
        const int r = hi - q;
        float x = (bufB[q] - Ub[r][1] * c1 - Ub[r][2] * c2 - Ub[r][3] * c3) * Ub[r][0];
        D[(size_t)r * NN + j] = x;
        c3 = c2; c2 = c1; c1 = x;
      }
      if (b + 3 < 16) {
        const int hin = 511 - 32 * (b + 3);
        #pragma unroll
        for (int q = 0; q < 32; ++q) bufB[q] = S[(size_t)(hin - q) * NN + j];
      }
    }
  }
}

// ------------- backward substitution + fused 64x64 LDS transpose -------------

__global__ __launch_bounds__(64) void k_bwdT(const float* __restrict__ src,
                                             float* __restrict__ dst) {
  const int lane = threadIdx.x;
  const int j0 = blockIdx.x * 64;
  const int j = j0 + lane;
  const size_t base = (size_t)blockIdx.y * (NN * NN);
  const float* __restrict__ S = src + base;
  float* __restrict__ D = dst + base;
  __shared__ float Ub[NN][4];
  __shared__ float tile[64][65];   // +1 pad: conflict-free transposed read
  for (int i = lane; i < NN; i += 64) {
    Ub[i][0] = g_tab.bandG[i * 8 + 3];
    Ub[i][1] = g_tab.bandG[i * 8 + 4];
    Ub[i][2] = g_tab.bandG[i * 8 + 5];
    Ub[i][3] = g_tab.bandG[i * 8 + 6];
  }
  __syncthreads();
  float c1 = 0.f, c2 = 0.f, c3 = 0.f;
  #pragma unroll 1
  for (int half = 0; half < 8; ++half) {
    const int hi = 511 - half * 64;
    float buf[64];
    #pragma unroll
    for (int q = 0; q < 64; ++q) buf[q] = S[(size_t)(hi - q) * NN + j];
    #pragma unroll
    for (int q = 0; q < 64; ++q) {
      const int r = hi - q;
      float x = (buf[q] - Ub[r][1] * c1 - Ub[r][2] * c2 - Ub[r][3] * c3) * Ub[r][0];
      tile[63 - q][lane] = x;
      c3 = c2; c2 = c1; c1 = x;
    }
    __syncthreads();
    const int lo = hi - 63;
    #pragma unroll 4
    for (int tt = 0; tt < 64; ++tt) {
      D[(size_t)(j0 + tt) * NN + lo + lane] = tile[lane][tt];
    }
    __syncthreads();
  }
}

// ------------- fused evaluation: H[p] = sum_q CoefT[q,p]*By[y,q]; out = Bx-sparse * H -------------

__global__ __launch_bounds__(256) void k_eval(const float* __restrict__ CoefT,
                                              float* __restrict__ out) {
  const int y = blockIdx.x;
  const int bc = blockIdx.y;
  const float* __restrict__ C = CoefT + (size_t)bc * (NN * NN);
  __shared__ float H[NN];
  const int tid = threadIdx.x;
  const int sy = g_tab.espan[y];
  const float4 wy = ((const float4*)g_tab.ebas)[y];
  #pragma unroll
  for (int pp = 0; pp < 2; ++pp) {
    const int p = tid + pp * 256;
    float h = wy.x * C[(size_t)(sy - 3) * NN + p]
            + wy.y * C[(size_t)(sy - 2) * NN + p]
            + wy.z * C[(size_t)(sy - 1) * NN + p]
            + wy.w * C[(size_t)(sy)     * NN + p];
    H[p] = h;
  }
  __syncthreads();
  float* __restrict__ O = out + ((size_t)bc * NE + y) * NE;
  #pragma unroll
  for (int xx = 0; xx < 4; ++xx) {
    const int x = tid + xx * 256;
    const int sx = g_tab.espan[x];
    const float4 wx = ((const float4*)g_tab.ebas)[x];
    O[x] = wx.x * H[sx - 3] + wx.y * H[sx - 2] + wx.z * H[sx - 1] + wx.w * H[sx];
  }
}

// ---------------- host launcher ----------------

extern "C" void kernel_launch(void* const* d_in, const int* in_sizes, int n_in,
                              void* d_out, int out_size, void* d_ws, size_t ws_size,
                              hipStream_t stream) {
  (void)in_sizes; (void)n_in; (void)out_size; (void)ws_size;
  const float* Z = (const float*)d_in[0];
  float* out = (float*)d_out;
  float* BUF2 = (float*)d_ws;      // 64 MB: X1^T then CoefT
  float* BUF1 = out;               // 64 MB scratch inside d_out (dead before k_eval)

  k_fwd <<<dim3(2, NBC),  dim3(256), 0, stream>>>(Z,    BUF1);   // L y = Z            (x-axis)
  k_bwdT<<<dim3(8, NBC),  dim3(64),  0, stream>>>(BUF1, BUF2);   // U x = y, write X1^T
  k_fwd <<<dim3(2, NBC),  dim3(256), 0, stream>>>(BUF2, BUF1);   // L y = X1^T         (y-axis)
  k_bwd <<<dim3(2, NBC),  dim3(256), 0, stream>>>(BUF1, BUF2);   // U x = y  -> CoefT
  k_eval<<<dim3(NE, NBC), dim3(256), 0, stream>>>(BUF2, out);
}

// Round 3
// 207.315 us; speedup vs baseline: 1.8337x; 1.1203x over previous
//
#include <hip/hip_runtime.h>

#define NN  512    // data grid / coefficient count per axis
#define NE  1024   // eval points per axis
#define NBC 64     // batch * channels
#define WH  8      // truncated-inverse half width
#define WT  17     // 2*WH+1 taps

// ================= compile-time table generation =================
// Mirrors the reference: x = float32 linspace(-1,1,512); knots via float32
// cumsum sliding mean; basis via de Boor in double; banded LU in double;
// then the TRUNCATED INVERSE band Gb[j][d] = Ainv[j][j-8+d] via windowed
// column solves (65 boundary columns exact + interior Toeplitz column).

struct Tables {
  float Gb[NN][WT];      // truncated A^-1 band, zero-padded
  int   espan[NE];
  float ebas[NE * 4];    // float4-aligned
};

constexpr int cfindspan(double u, const float* t) {
  if (u >= (double)t[NN]) return NN - 1;          // t[512] == 1.0
  int lo = 3, hi = NN - 1;
  while (lo < hi) {
    int mid = (lo + hi + 1) >> 1;
    if ((double)t[mid] <= u) lo = mid; else hi = mid - 1;
  }
  return lo;
}

constexpr void cdeboor4(double u, const float* t, int s, double* N) {
  double left[4] = {}, right[4] = {};
  N[0] = 1.0; N[1] = 0.0; N[2] = 0.0; N[3] = 0.0;
  for (int d = 1; d <= 3; ++d) {
    left[d]  = u - (double)t[s + 1 - d];
    right[d] = (double)t[s + d] - u;
    double saved = 0.0;
    for (int r = 0; r < d; ++r) {
      double temp = N[r] / (right[r + 1] + left[d - r]);
      N[r] = saved + right[r + 1] * temp;
      saved = left[d - r] * temp;
    }
    N[d] = saved;
  }
}

constexpr Tables make_tables() {
  Tables T{};
  // x grid (float32, matches jnp.linspace(-1,1,512))
  float x[NN] = {};
  for (int i = 0; i < NN; ++i) x[i] = (float)(-1.0 + (2.0 * i) / 511.0);
  x[0] = -1.0f; x[NN - 1] = 1.0f;
  // fitpack knots: float32 cumsum, interior = sliding mean of 3
  float t[NN + 4] = {};
  {
    float cs[NN + 1] = {};
    for (int i = 0; i < NN; ++i) cs[i + 1] = cs[i] + x[i];
    for (int i = 0; i < NN - 4; ++i) t[4 + i] = (cs[4 + i] - cs[1 + i]) / 3.0f;
    for (int i = 0; i < 4; ++i) { t[i] = -1.0f; t[NN + i] = 1.0f; }
  }
  // banded collocation matrix (double), band offset d = col - r + 3
  double W[NN][7] = {};
  for (int r = 0; r < NN; ++r) {
    double u = (double)x[r];
    int s = cfindspan(u, t);
    double N[4] = {};
    cdeboor4(u, t, s, N);
    for (int dd = 0; dd < 4; ++dd) W[r][s - r + dd] += N[dd];
  }
  // banded LU (bw 3/3): lower entries become L multipliers; [3]=U diag; [4..6]=U supers
  for (int r = 0; r < NN; ++r) {
    double rd = 1.0 / W[r][3];
    for (int k = 1; k <= 3; ++k) {
      if (r + k < NN) {
        double l = W[r + k][3 - k] * rd;
        W[r + k][3 - k] = l;
        for (int cc = 1; cc <= 3; ++cc) W[r + k][3 - k + cc] -= l * W[r][3 + cc];
      }
    }
  }
  // ---- truncated inverse band ----
  // pass 0: boundary columns y in [0,32) -> rows j < 24
  // pass 1: boundary columns y in [480,512) -> rows j >= 488
  // pass 2: y = 256 -> interior Toeplitz vector tv
  double tv[WT] = {};
  for (int pass = 0; pass < 3; ++pass) {
    const int ylo = (pass == 0) ? 0 : (pass == 1) ? 480 : 256;
    const int yhi = (pass == 0) ? 32 : (pass == 1) ? 512 : 257;
    for (int y = ylo; y < yhi; ++y) {
      // forward: w = L^-1 e_y on window [y, rend] (exact: w=0 above y)
      double wv[21] = {};
      int rend = y + 20; if (rend > NN - 1) rend = NN - 1;
      wv[0] = 1.0;
      for (int r = y + 1; r <= rend; ++r) {
        double acc = 0.0;
        if (r - 1 >= y) acc += W[r][2] * wv[r - 1 - y];
        if (r - 2 >= y) acc += W[r][1] * wv[r - 2 - y];
        if (r - 3 >= y) acc += W[r][0] * wv[r - 3 - y];
        wv[r - y] = -acc;
      }
      // backward: g = U^-1 w, assuming g=0 beyond rend (error ~0.268^12)
      double g[29] = {};
      int glo = y - WH; if (glo < 0) glo = 0;
      for (int r = rend; r >= glo; --r) {
        double acc = (r >= y) ? wv[r - y] : 0.0;
        if (r + 1 <= rend) acc -= W[r][4] * g[r + 1 - (y - WH)];
        if (r + 2 <= rend) acc -= W[r][5] * g[r + 2 - (y - WH)];
        if (r + 3 <= rend) acc -= W[r][6] * g[r + 3 - (y - WH)];
        g[r - (y - WH)] = acc / W[r][3];
      }
      if (pass == 2) {
        for (int d = 0; d < WT; ++d) tv[d] = g[16 - d];   // Ainv[256+8-d, 256]
      } else {
        int jlo = y - WH; if (jlo < 0) jlo = 0;
        int jhi = y + WH; if (jhi > NN - 1) jhi = NN - 1;
        for (int j = jlo; j <= jhi; ++j) {
          const bool bdry = (pass == 0) ? (j < 24) : (j >= 488);
          if (bdry) T.Gb[j][y - j + WH] = (float)g[j - (y - WH)];
        }
      }
    }
  }
  for (int j = 24; j < 488; ++j)
    for (int d = 0; d < WT; ++d) T.Gb[j][d] = (float)tv[d];
  // eval-point basis (1024 points)
  for (int i = 0; i < NE; ++i) {
    float xe = (float)(-1.0 + (2.0 * i) / 1023.0);
    if (i == 0) xe = -1.0f;
    if (i == NE - 1) xe = 1.0f;
    double u = (double)xe;
    int s = cfindspan(u, t);
    double N[4] = {};
    cdeboor4(u, t, s, N);
    T.espan[i] = s;
    T.ebas[i * 4 + 0] = (float)N[0];
    T.ebas[i * 4 + 1] = (float)N[1];
    T.ebas[i * 4 + 2] = (float)N[2];
    T.ebas[i * 4 + 3] = (float)N[3];
  }
  return T;
}

__constant__ Tables g_tab = make_tables();

// ------------- K1: contract y (17-tap band), fused transpose -------------
// S2T[bc][j][x] = sum_d Gb[j][d] * Z[bc][x][j-8+d]

__global__ __launch_bounds__(256) void k_conv1(const float* __restrict__ Z,
                                               float* __restrict__ S2T) {
  const int xt = blockIdx.x * 64;
  const int jt = blockIdx.y * 64;
  const int bc = blockIdx.z;
  const float* __restrict__ src = Z + (size_t)bc * (NN * NN);
  __shared__ float in[64][88];   // y-window [jt-8, jt+72) at col (y-(jt-8)); 88 = pad, 16B-aligned rows
  __shared__ float tr[64][65];   // transpose buffer (+1 pad)
  const int tid = threadIdx.x;
  const int jqi = tid & 15;
  // per-thread coefficient cache: 4 consecutive j rows
  float c[4][WT];
  #pragma unroll
  for (int q = 0; q < 4; ++q)
    #pragma unroll
    for (int d = 0; d < WT; ++d)
      c[q][d] = g_tab.Gb[jt + jqi * 4 + q][d];
  // load input tile: 64 rows x 80 cols (zero-padded at grid edges)
  for (int u = tid; u < 64 * 20; u += 256) {
    const int r = u / 20, c4 = u % 20;
    const int y0 = jt - 8 + c4 * 4;
    float4 v;
    if (y0 >= 0 && y0 + 4 <= NN) {
      v = *(const float4*)&src[(size_t)(xt + r) * NN + y0];
    } else {
      float e0 = (y0 + 0 >= 0 && y0 + 0 < NN) ? src[(size_t)(xt + r) * NN + y0 + 0] : 0.f;
      float e1 = (y0 + 1 >= 0 && y0 + 1 < NN) ? src[(size_t)(xt + r) * NN + y0 + 1] : 0.f;
      float e2 = (y0 + 2 >= 0 && y0 + 2 < NN) ? src[(size_t)(xt + r) * NN + y0 + 2] : 0.f;
      float e3 = (y0 + 3 >= 0 && y0 + 3 < NN) ? src[(size_t)(xt + r) * NN + y0 + 3] : 0.f;
      v = make_float4(e0, e1, e2, e3);
    }
    *(float4*)&in[r][c4 * 4] = v;
  }
  __syncthreads();
  #pragma unroll
  for (int p = 0; p < 4; ++p) {
    const int xl = (tid >> 4) + p * 16;
    float w[20];
    #pragma unroll
    for (int e = 0; e < 5; ++e)
      *(float4*)&w[e * 4] = *(const float4*)&in[xl][jqi * 4 + e * 4];
    float4 a = make_float4(0.f, 0.f, 0.f, 0.f);
    #pragma unroll
    for (int d = 0; d < WT; ++d) {
      a.x += c[0][d] * w[0 + d];
      a.y += c[1][d] * w[1 + d];
      a.z += c[2][d] * w[2 + d];
      a.w += c[3][d] * w[3 + d];
    }
    tr[jqi * 4 + 0][xl] = a.x;
    tr[jqi * 4 + 1][xl] = a.y;
    tr[jqi * 4 + 2][xl] = a.z;
    tr[jqi * 4 + 3][xl] = a.w;
  }
  __syncthreads();
  float* __restrict__ dst = S2T + (size_t)bc * (NN * NN);
  for (int u = tid; u < 64 * 16; u += 256) {
    const int jr = u >> 4, x4 = (u & 15) * 4;
    float4 v = make_float4(tr[jr][x4 + 0], tr[jr][x4 + 1], tr[jr][x4 + 2], tr[jr][x4 + 3]);
    *(float4*)&dst[(size_t)(jt + jr) * NN + xt + x4] = v;
  }
}

// ------------- K2: contract x (17-tap band), natural layout -------------
// CT[bc][j][i] = sum_d Gb[i][d] * S2T[bc][j][i-8+d]   ( = Coef[i][j] )

__global__ __launch_bounds__(256) void k_conv2(const float* __restrict__ S2T,
                                               float* __restrict__ CT) {
  const int it = blockIdx.x * 64;
  const int jt = blockIdx.y * 64;
  const int bc = blockIdx.z;
  const float* __restrict__ src = S2T + (size_t)bc * (NN * NN);
  __shared__ float in[64][88];   // x-window [it-8, it+72)
  const int tid = threadIdx.x;
  const int iqi = tid & 15;
  float c[4][WT];
  #pragma unroll
  for (int q = 0; q < 4; ++q)
    #pragma unroll
    for (int d = 0; d < WT; ++d)
      c[q][d] = g_tab.Gb[it + iqi * 4 + q][d];
  for (int u = tid; u < 64 * 20; u += 256) {
    const int r = u / 20, c4 = u % 20;
    const int x0 = it - 8 + c4 * 4;
    float4 v;
    if (x0 >= 0 && x0 + 4 <= NN) {
      v = *(const float4*)&src[(size_t)(jt + r) * NN + x0];
    } else {
      float e0 = (x0 + 0 >= 0 && x0 + 0 < NN) ? src[(size_t)(jt + r) * NN + x0 + 0] : 0.f;
      float e1 = (x0 + 1 >= 0 && x0 + 1 < NN) ? src[(size_t)(jt + r) * NN + x0 + 1] : 0.f;
      float e2 = (x0 + 2 >= 0 && x0 + 2 < NN) ? src[(size_t)(jt + r) * NN + x0 + 2] : 0.f;
      float e3 = (x0 + 3 >= 0 && x0 + 3 < NN) ? src[(size_t)(jt + r) * NN + x0 + 3] : 0.f;
      v = make_float4(e0, e1, e2, e3);
    }
    *(float4*)&in[r][c4 * 4] = v;
  }
  __syncthreads();
  float* __restrict__ dst = CT + (size_t)bc * (NN * NN);
  #pragma unroll
  for (int p = 0; p < 4; ++p) {
    const int jl = (tid >> 4) + p * 16;
    float w[20];
    #pragma unroll
    for (int e = 0; e < 5; ++e)
      *(float4*)&w[e * 4] = *(const float4*)&in[jl][iqi * 4 + e * 4];
    float4 a = make_float4(0.f, 0.f, 0.f, 0.f);
    #pragma unroll
    for (int d = 0; d < WT; ++d) {
      a.x += c[0][d] * w[0 + d];
      a.y += c[1][d] * w[1 + d];
      a.z += c[2][d] * w[2 + d];
      a.w += c[3][d] * w[3 + d];
    }
    *(float4*)&dst[(size_t)(jt + jl) * NN + it + iqi * 4] = a;
  }
}

// ------------- K3: fused evaluation -------------
// H[p] = sum_q CT[sy-3+q][p]*wy[q];  out[f][t] = 4-tap x-combination of H

__global__ __launch_bounds__(256) void k_eval(const float* __restrict__ CoefT,
                                              float* __restrict__ out) {
  const int y = blockIdx.x;    // output row f
  const int bc = blockIdx.y;
  const float* __restrict__ C = CoefT + (size_t)bc * (NN * NN);
  __shared__ float H[NN];
  const int tid = threadIdx.x;
  const int sy = g_tab.espan[y];
  const float4 wy = *(const float4*)&g_tab.ebas[y * 4];
  #pragma unroll
  for (int pp = 0; pp < 2; ++pp) {
    const int p = tid + pp * 256;
    H[p] = wy.x * C[(size_t)(sy - 3) * NN + p]
         + wy.y * C[(size_t)(sy - 2) * NN + p]
         + wy.z * C[(size_t)(sy - 1) * NN + p]
         + wy.w * C[(size_t)(sy)     * NN + p];
  }
  __syncthreads();
  float* __restrict__ O = out + ((size_t)bc * NE + y) * NE;
  const int x0 = tid * 4;
  float4 o;
  #pragma unroll
  for (int e = 0; e < 4; ++e) {
    const int x = x0 + e;
    const int sx = g_tab.espan[x];
    const float4 wx = *(const float4*)&g_tab.ebas[x * 4];
    (&o.x)[e] = wx.x * H[sx - 3] + wx.y * H[sx - 2] + wx.z * H[sx - 1] + wx.w * H[sx];
  }
  *(float4*)&O[x0] = o;
}

// ---------------- host launcher ----------------

extern "C" void kernel_launch(void* const* d_in, const int* in_sizes, int n_in,
                              void* d_out, int out_size, void* d_ws, size_t ws_size,
                              hipStream_t stream) {
  (void)in_sizes; (void)n_in; (void)out_size; (void)ws_size;
  const float* Z = (const float*)d_in[0];
  float* out = (float*)d_out;
  float* S2T = out;               // 64 MB scratch inside d_out (dead before k_eval)
  float* CT  = (float*)d_ws;      // 64 MB

  k_conv1<<<dim3(8, 8, NBC), 256, 0, stream>>>(Z,   S2T);  // contract y + transpose
  k_conv2<<<dim3(8, 8, NBC), 256, 0, stream>>>(S2T, CT);   // contract x -> CoefT
  k_eval <<<dim3(NE, NBC),   256, 0, stream>>>(CT,  out);  // 4x4-tap evaluation
}